// Round 1
// baseline (678.993 us; speedup 1.0000x reference)
//
#include <hip/hip_runtime.h>
#include <cstdint>
#include <cstddef>

typedef unsigned short u16;
typedef __bf16 bf16x8 __attribute__((ext_vector_type(8)));
typedef float f32x4 __attribute__((ext_vector_type(4)));

__device__ __forceinline__ u16 f2bf(float f) {
  uint32_t u = __builtin_bit_cast(uint32_t, f);
  u += 0x7FFFu + ((u >> 16) & 1u);   // round-to-nearest-even
  return (u16)(u >> 16);
}
__device__ __forceinline__ float bf2f(u16 h) {
  return __builtin_bit_cast(float, (uint32_t)h << 16);
}

// ---------------- kernel 1: logmap0  (x f32 -> x_tan bf16) ----------------
// scale = artanh(clip(||x||,0.99)) / max(||x||,1e-15); x_tan = clip(scale*x, +-50)
__global__ __launch_bounds__(256) void k_logmap0(const float* __restrict__ x,
                                                 u16* __restrict__ xt) {
  const size_t row = blockIdx.x;
  float4 v = ((const float4*)(x + row * 1024))[threadIdx.x];
  float ss = v.x * v.x + v.y * v.y + v.z * v.z + v.w * v.w;
#pragma unroll
  for (int off = 32; off > 0; off >>= 1) ss += __shfl_down(ss, off, 64);
  __shared__ float wsum[4];
  if ((threadIdx.x & 63) == 0) wsum[threadIdx.x >> 6] = ss;
  __syncthreads();
  float tot = wsum[0] + wsum[1] + wsum[2] + wsum[3];
  float n = fmaxf(sqrtf(tot), 1e-15f);
  float arg = fminf(n, 0.99f);                               // clip(sqrt_c*norm, +-0.99), n>=0
  float xc = fminf(fmaxf(arg, -0.99f + 1e-7f), 0.99f - 1e-7f); // artanh internal clamp
  float at = 0.5f * (log1pf(xc) - log1pf(-xc));
  float scale = at / n;
  ushort4 o;
  o.x = f2bf(fminf(fmaxf(scale * v.x, -50.f), 50.f));
  o.y = f2bf(fminf(fmaxf(scale * v.y, -50.f), 50.f));
  o.z = f2bf(fminf(fmaxf(scale * v.z, -50.f), 50.f));
  o.w = f2bf(fminf(fmaxf(scale * v.w, -50.f), 50.f));
  ((ushort4*)(xt + row * 1024))[threadIdx.x] = o;
}

// ---------------- kernel 2: m f32 -> bf16 ----------------
__global__ __launch_bounds__(256) void k_cvt_m(const float* __restrict__ m,
                                               u16* __restrict__ mb) {
  int i = blockIdx.x * 256 + threadIdx.x;
  float4 v = ((const float4*)m)[i];
  ushort4 o;
  o.x = f2bf(v.x); o.y = f2bf(v.y); o.z = f2bf(v.z); o.w = f2bf(v.w);
  ((ushort4*)mb)[i] = o;
}

// ---------------- kernel 3: C[i,j] = sum_k A[i,k]*B[j,k]  (bf16 in, bf16 out) --------
// m97 structure: 128x128 tile, BK=32, 4 waves (2x2 of 64x64), 16x16x32 bf16 MFMA,
// global_load_lds width-16 staging (LDS dest = wave-uniform base + lane*16).
__global__ __launch_bounds__(256) void k_gemm_bt(const u16* __restrict__ A,
                                                 const u16* __restrict__ B,
                                                 u16* __restrict__ C,
                                                 int Kdim) {
  __shared__ alignas(16) u16 As[128 * 32];
  __shared__ alignas(16) u16 Bs[128 * 32];
  const int tid = threadIdx.x;
  const int lane = tid & 63;
  const int wave = tid >> 6;
  const size_t row0 = (size_t)blockIdx.x * 128;
  const int col0 = blockIdx.y * 128;
  const int wm = (wave & 1) * 64;
  const int wn = (wave >> 1) * 64;

  // staging: thread t covers A/B[row = t>>2 (+64)], k-chunk (t&3)*8 (16 B)
  const int s_row = tid >> 2;
  const int s_k = (tid & 3) * 8;
  const u16* aP = A + (row0 + s_row) * (size_t)Kdim + s_k;
  const u16* bP = B + (size_t)(col0 + s_row) * Kdim + s_k;
  const size_t rstep = (size_t)64 * Kdim;
  u16* AsW0 = As + wave * 512;         // bytes: wave*1024 (+ lane*16 by HW)
  u16* AsW1 = As + 2048 + wave * 512;  // rows 64..127
  u16* BsW0 = Bs + wave * 512;
  u16* BsW1 = Bs + 2048 + wave * 512;

  // fragment LDS addrs: lane holds [m|n = lane&15][k = (lane>>4)*8 .. +8]
  const int frow = lane & 15;
  const int fk = (lane >> 4) * 8;
  const u16* aF = As + (wm + frow) * 32 + fk;
  const u16* bF = Bs + (wn + frow) * 32 + fk;

  f32x4 acc[4][4];
#pragma unroll
  for (int i = 0; i < 4; ++i)
#pragma unroll
    for (int j = 0; j < 4; ++j) {
      f32x4 z = {0.f, 0.f, 0.f, 0.f};
      acc[i][j] = z;
    }

  for (int k0 = 0; k0 < Kdim; k0 += 32) {
    __syncthreads();  // previous tile fully consumed
    __builtin_amdgcn_global_load_lds(
        (const __attribute__((address_space(1))) void*)(aP + k0),
        (__attribute__((address_space(3))) void*)AsW0, 16, 0, 0);
    __builtin_amdgcn_global_load_lds(
        (const __attribute__((address_space(1))) void*)(aP + k0 + rstep),
        (__attribute__((address_space(3))) void*)AsW1, 16, 0, 0);
    __builtin_amdgcn_global_load_lds(
        (const __attribute__((address_space(1))) void*)(bP + k0),
        (__attribute__((address_space(3))) void*)BsW0, 16, 0, 0);
    __builtin_amdgcn_global_load_lds(
        (const __attribute__((address_space(1))) void*)(bP + k0 + rstep),
        (__attribute__((address_space(3))) void*)BsW1, 16, 0, 0);
    __syncthreads();  // drains vmcnt -> staged tile visible

    bf16x8 af[4], bfr[4];
#pragma unroll
    for (int i = 0; i < 4; ++i) af[i] = *(const bf16x8*)(aF + i * 512);
#pragma unroll
    for (int j = 0; j < 4; ++j) bfr[j] = *(const bf16x8*)(bF + j * 512);
#pragma unroll
    for (int i = 0; i < 4; ++i)
#pragma unroll
      for (int j = 0; j < 4; ++j)
        acc[i][j] = __builtin_amdgcn_mfma_f32_16x16x32_bf16(af[i], bfr[j],
                                                            acc[i][j], 0, 0, 0);
  }

  // epilogue: clip(+-1000) -> bf16.  C/D map: col=lane&15, row=(lane>>4)*4+r
#pragma unroll
  for (int i = 0; i < 4; ++i) {
    size_t rb = row0 + wm + i * 16 + (lane >> 4) * 4;
#pragma unroll
    for (int j = 0; j < 4; ++j) {
      int cc = col0 + wn + j * 16 + (lane & 15);
#pragma unroll
      for (int r = 0; r < 4; ++r) {
        float v = fminf(fmaxf(acc[i][j][r], -1000.f), 1000.f);
        C[(rb + r) * 1024 + cc] = f2bf(v);
      }
    }
  }
}

// ---------------- kernel 4: expmap0 + proj  (mx bf16 -> out f32) ----------------
__global__ __launch_bounds__(256) void k_expmap_proj(const u16* __restrict__ mx,
                                                     float* __restrict__ out) {
  const size_t row = blockIdx.x;
  ushort4 q = ((const ushort4*)(mx + row * 1024))[threadIdx.x];
  float u0 = bf2f(q.x), u1 = bf2f(q.y), u2 = bf2f(q.z), u3 = bf2f(q.w);
  float ss = u0 * u0 + u1 * u1 + u2 * u2 + u3 * u3;
#pragma unroll
  for (int off = 32; off > 0; off >>= 1) ss += __shfl_down(ss, off, 64);
  __shared__ float wsum[4];
  if ((threadIdx.x & 63) == 0) wsum[threadIdx.x >> 6] = ss;
  __syncthreads();
  float tot = wsum[0] + wsum[1] + wsum[2] + wsum[3];
  float n = fmaxf(sqrtf(tot), 1e-15f);
  float t = tanhf(n);
  float scale = t / n;                  // expmap0: tanh(||u||)*u/||u||
  float ynorm = t;                      // ||expmap0(u)|| = tanh(n) exactly
  const float max_norm = 1.0f - 1e-10f; // proj threshold (folds to 1.0f, same as ref f32)
  if (ynorm > max_norm) scale *= max_norm / fmaxf(ynorm, 1e-9f);
  float4 o;
  o.x = scale * u0; o.y = scale * u1; o.z = scale * u2; o.w = scale * u3;
  ((float4*)(out + row * 1024))[threadIdx.x] = o;
}

extern "C" void kernel_launch(void* const* d_in, const int* in_sizes, int n_in,
                              void* d_out, int out_size, void* d_ws, size_t ws_size,
                              hipStream_t stream) {
  const float* x = (const float*)d_in[0];
  const float* m = (const float*)d_in[1];
  float* out = (float*)d_out;
  const int K = 1024, N = 1024;
  const int M = in_sizes[0] / K;  // 65536

  // workspace layout: [0,2MB) m_bf16 ; [2MB, 2MB+128MB) mx bf16   (needs ~130 MB)
  u16* mb = (u16*)d_ws;
  u16* mx = (u16*)d_ws + (size_t)N * K;
  // x_tan bf16 lives in the lower half of d_out (dead until kernel 4 overwrites)
  u16* xt = (u16*)d_out;

  k_logmap0<<<M, 256, 0, stream>>>(x, xt);
  k_cvt_m<<<(N * K / 4) / 256, 256, 0, stream>>>(m, mb);
  dim3 g(M / 128, N / 128);  // linear%8 == bm%8 -> 8 n-tiles of one A-panel share an XCD
  k_gemm_bt<<<g, 256, 0, stream>>>(xt, mb, mx, K);
  k_expmap_proj<<<M, 256, 0, stream>>>(mx, out);
}